// Round 1
// baseline (3239.688 us; speedup 1.0000x reference)
//
#include <hip/hip_runtime.h>

// Problem constants (match reference)
#define C_CH 16
#define H_DIM 1024
#define W_DIM 1024
#define HW (H_DIM * W_DIM)
#define L_PTS 4000000

// Kernel 1: copy x (as float4) into out. 16M floats = 4M float4.
__global__ void copy_x_kernel(const float4* __restrict__ src,
                              float4* __restrict__ dst, int n4) {
    int i = blockIdx.x * blockDim.x + threadIdx.x;
    if (i < n4) dst[i] = src[i];
}

// Kernel 2: one thread per point l. Coalesced index loads, then 16 gathers
// + 16 device-scope atomicAdds (random addresses; L2/L3 absorb reuse).
__global__ void scatter_add_kernel(const float* __restrict__ img,
                                   const int* __restrict__ index_x,
                                   const int* __restrict__ index_y,
                                   const int* __restrict__ proj_x,
                                   const int* __restrict__ proj_y,
                                   float* __restrict__ out, int L) {
    int l = blockIdx.x * blockDim.x + threadIdx.x;
    if (l >= L) return;
    const int ix = index_x[l];   // row into H of out
    const int iy = index_y[l];   // col into W of out
    const int px = proj_x[l];    // col into W of img
    const int py = proj_y[l];    // row into H of img

    const int src = py * W_DIM + px;
    const int dst = ix * W_DIM + iy;

    #pragma unroll
    for (int c = 0; c < C_CH; ++c) {
        const float v = img[c * HW + src];
        atomicAdd(out + c * HW + dst, v);
    }
}

extern "C" void kernel_launch(void* const* d_in, const int* in_sizes, int n_in,
                              void* d_out, int out_size, void* d_ws, size_t ws_size,
                              hipStream_t stream) {
    const float* x       = (const float*)d_in[0]; // (1,16,1024,1024)
    const float* img     = (const float*)d_in[1]; // (16,1024,1024)
    const int*   index_x = (const int*)d_in[2];   // (L,1)
    const int*   index_y = (const int*)d_in[3];   // (L,1)
    const int*   proj_x  = (const int*)d_in[4];   // (L,)
    const int*   proj_y  = (const int*)d_in[5];   // (L,)
    float* out = (float*)d_out;                   // (16,1024,1024)

    // 1) out = x
    const int n4 = (C_CH * HW) / 4;
    {
        const int block = 256;
        const int grid = (n4 + block - 1) / block;
        copy_x_kernel<<<grid, block, 0, stream>>>((const float4*)x, (float4*)out, n4);
    }

    // 2) scatter-add
    {
        const int block = 256;
        const int grid = (L_PTS + block - 1) / block;
        scatter_add_kernel<<<grid, block, 0, stream>>>(img, index_x, index_y,
                                                       proj_x, proj_y, out, L_PTS);
    }
}